// Round 3
// baseline (16345.464 us; speedup 1.0000x reference)
//
#include <hip/hip_runtime.h>

#define NWG   256
#define NTHR  512
#define TSEQ  512
#define HID   1024
#define NCLS  32000
#define KP1   2056   // padded LDS row stride (elements), layer 1 (K=2048)
#define KP0   1544   // padded LDS row stride (elements), layer 0 (K=1536)

typedef __attribute__((ext_vector_type(8))) short short8;
typedef __attribute__((ext_vector_type(4))) float floatx4;

struct AB { short8 a[4]; short8 b[2]; };

__device__ __forceinline__ unsigned short f2bf(float f) {
  union { float f; unsigned u; } c; c.f = f;
  unsigned r = c.u + 0x7fffu + ((c.u >> 16) & 1u);
  return (unsigned short)(r >> 16);
}
__device__ __forceinline__ float sigmoidf_(float x) {
  x = fminf(30.f, fmaxf(-30.f, x));
  return 1.f / (1.f + __expf(-x));
}
__device__ __forceinline__ float tanhf_(float x) {
  x = fminf(15.f, fmaxf(-15.f, x));
  float e = __expf(2.f * x);
  return (e - 1.f) / (e + 1.f);
}

__device__ __forceinline__ void mfma8(const AB& f, floatx4 (&acc)[4][2]) {
#pragma unroll
  for (int mt = 0; mt < 4; ++mt)
#pragma unroll
    for (int nt = 0; nt < 2; ++nt)
      acc[mt][nt] = __builtin_amdgcn_mfma_f32_16x16x32_bf16(f.a[mt], f.b[nt], acc[mt][nt], 0, 0, 0);
}

// One wave's K-slice of C[64,32] += A[64,Kslice] * W^T.  A from global (bf16),
// W from LDS (bf16, row-major [32][KPAD]).  hb pre-shifted so addr = hb + k for k>=kx.
template <int NKT, int KPAD>
__device__ __forceinline__ void gemm_step(
    int kb, int kx, int keo, int lm,
    const unsigned short* const (&xb)[4], const unsigned short* const (&hb)[4],
    const unsigned short* wl, floatx4 (&acc)[4][2])
{
  AB f0, f1;
  auto ld = [&](AB& f, int kt) {
    const int k = kb + kt * 32;
    const int off = k + keo;
#pragma unroll
    for (int nt = 0; nt < 2; ++nt)
      f.b[nt] = *reinterpret_cast<const short8*>(wl + (nt * 16 + lm) * KPAD + off);
    const bool inx = k < kx;   // wave-uniform; 32-tiles never straddle kx
#pragma unroll
    for (int mt = 0; mt < 4; ++mt)
      f.a[mt] = *reinterpret_cast<const short8*>((inx ? xb[mt] : hb[mt]) + off);
  };
  ld(f0, 0);
#pragma unroll
  for (int kt = 0; kt + 2 < NKT; kt += 2) {
    ld(f1, kt + 1);
    mfma8(f0, acc);
    ld(f0, kt + 2);
    mfma8(f1, acc);
  }
  ld(f1, NKT - 1);
  mfma8(f0, acc);
  mfma8(f1, acc);
}

__global__ void __launch_bounds__(NTHR, 1)
lstm_kernel(const int* __restrict__ feat,
            const float* __restrict__ emb,
            const float* __restrict__ wih0, const float* __restrict__ whh0,
            const float* __restrict__ bih0, const float* __restrict__ bhh0,
            const float* __restrict__ wih1, const float* __restrict__ whh1,
            const float* __restrict__ bih1, const float* __restrict__ bhh1,
            const float* __restrict__ fcw, const float* __restrict__ fcb,
            float* __restrict__ out,
            unsigned* __restrict__ bar)
{
  const int tid  = threadIdx.x;
  const int wg   = blockIdx.x;
  const int wave = tid >> 6;
  const int lane = tid & 63;
  const int quad = lane >> 4;
  const int lm   = lane & 15;
  const int keo  = quad * 8;

  // bf16 scratch inside d_out (f32 [64,32000] = 8.19 MB); FC overwrites at end.
  unsigned short* sc   = (unsigned short*)out;
  unsigned short* h0   = sc;              // 2 x [64][1024]
  unsigned short* h1   = sc + 131072;     // 2 x [64][1024]
  unsigned short* lh   = sc + 262144;     // [64][1024]
  unsigned short* xbuf = sc + 327680;     // 2 x [64][512]

  const int layer = (wg >= 128) ? 1 : 0;
  const int wl_id = wg & 127;
  const int jb = wl_id * 8;               // this WG owns H-columns [jb, jb+8)

  __shared__ unsigned short wlds[32 * KP1];  // 131,584 B: this WG's weights, bf16
  __shared__ float red[4][32][40];           // 20,480 B: K-split partials (bank-tuned)
  __shared__ int   sl[64];

  // ---- one-time: weights f32 -> bf16 -> LDS  (rows r: gate=r>>3, col=jb+(r&7)) ----
  {
    const float* wih = layer ? wih1 : wih0;
    const float* whh = layer ? whh1 : whh0;
    const int KX   = layer ? 1024 : 512;
    const int KTOT = layer ? 2048 : 1536;
    const int KPAD = layer ? KP1 : KP0;
    for (int r = 0; r < 32; ++r) {
      const int gr = (r >> 3) * HID + jb + (r & 7);
      for (int e4 = tid; e4 < (KTOT >> 2); e4 += NTHR) {
        const int k = e4 * 4;
        float4 v = (k < KX) ? *(const float4*)(wih + (size_t)gr * KX + k)
                            : *(const float4*)(whh + (size_t)gr * 1024 + (k - KX));
        ushort4 u; u.x = f2bf(v.x); u.y = f2bf(v.y); u.z = f2bf(v.z); u.w = f2bf(v.w);
        *(ushort4*)(wlds + r * KPAD + k) = u;
      }
    }
    if (layer && tid < 64) {   // seq_lens
      int cnt = 0;
      const int* fr = feat + tid * TSEQ;
      for (int k = 0; k < TSEQ; k += 4)
        cnt += (fr[k] != 31999) + (fr[k + 1] != 31999) +
               (fr[k + 2] != 31999) + (fr[k + 3] != 31999);
      int v = cnt - 1; if (v < 0) v = 0;
      sl[tid] = v;
    }
  }
  __syncthreads();

  // ---- per-cell-thread persistent state (tid<256: b = half*32 + (tid>>3), jl = tid&7)
  float bsum[4];
  float cv[2] = {0.f, 0.f};
  int   slv[2] = {0, 0};
  const int jl_c = tid & 7;
  const int bl_c = tid >> 3;     // 0..31 for tid<256
  if (tid < 256) {
    const float* bih = layer ? bih1 : bih0;
    const float* bhh = layer ? bhh1 : bhh0;
    const int gj = jb + jl_c;
#pragma unroll
    for (int g = 0; g < 4; ++g) bsum[g] = bih[g * HID + gj] + bhh[g * HID + gj];
    if (layer) { slv[0] = sl[bl_c]; slv[1] = sl[32 + bl_c]; }
  }

  // ---- pre-fill xbuf slot 0 with t=0 (layer-0 WGs: WG wl_id -> batch wl_id>>1, half wl_id&1)
  if (!layer && tid < 256) {
    const int b = wl_id >> 1;
    const int off = (wl_id & 1) * 256 + tid;
    xbuf[b * 512 + off] = f2bf(emb[(size_t)feat[b * TSEQ + 0] * 512 + off]);
  }

  unsigned target = 0;
  auto grid_barrier = [&]() {
    ++target;
    __syncthreads();
    if (tid == 0) {
      __builtin_amdgcn_fence(__ATOMIC_RELEASE, "agent");
      unsigned old = __hip_atomic_fetch_add(&bar[0], 1u, __ATOMIC_RELAXED, __HIP_MEMORY_SCOPE_AGENT);
      if (old == NWG - 1) {
        __hip_atomic_store(&bar[0], 0u, __ATOMIC_RELAXED, __HIP_MEMORY_SCOPE_AGENT);
        __hip_atomic_store(&bar[1], target, __ATOMIC_RELEASE, __HIP_MEMORY_SCOPE_AGENT);
      } else {
        while (__hip_atomic_load(&bar[1], __ATOMIC_ACQUIRE, __HIP_MEMORY_SCOPE_AGENT) < target) {
          __builtin_amdgcn_s_sleep(2);
        }
      }
      __builtin_amdgcn_fence(__ATOMIC_ACQUIRE, "agent");
    }
    __syncthreads();
  };

  grid_barrier();   // xbuf[0] visible to all layer-0 WGs

  const int KW = layer ? 256 : 192;    // K per wave (8-way K-split)
  const int kb = wave * KW;

  for (int s = 0; s <= TSEQ; ++s) {
    const bool active = layer ? (s >= 1) : (s < TSEQ);
    const int t = layer ? (s - 1) : s;

    if (active) {
      // stage next x_t (layer-0 only): 1 element per thread
      if (!layer && (s + 1 < TSEQ) && tid < 256) {
        const int b = wl_id >> 1;
        const int off = (wl_id & 1) * 256 + tid;
        xbuf[((s + 1) & 1) * 32768 + b * 512 + off] =
            f2bf(emb[(size_t)feat[b * TSEQ + (s + 1)] * 512 + off]);
      }

      // A-source pointers for this step
      const unsigned short* xb[4];
      const unsigned short* hb[4];
      unsigned short* hw;
      if (layer) {
        const unsigned short* h0r = h0 + (size_t)((s - 1) & 1) * 65536;  // layer-0 out @ t
        const unsigned short* h1r = h1 + (size_t)(s & 1) * 65536;        // own prev h (t-1)
#pragma unroll
        for (int mt = 0; mt < 4; ++mt) {
          const int row = mt * 16 + lm;
          xb[mt] = h0r + row * HID;
          hb[mt] = h1r + row * HID - 1024;
        }
        hw = h1 + (size_t)(t & 1) * 65536;
      } else {
        const unsigned short* xq  = xbuf + (size_t)(s & 1) * 32768;
        const unsigned short* h0r = h0 + (size_t)((s + 1) & 1) * 65536;
#pragma unroll
        for (int mt = 0; mt < 4; ++mt) {
          const int row = mt * 16 + lm;
          xb[mt] = xq + row * 512;
          hb[mt] = h0r + row * HID - 512;
        }
        hw = h0 + (size_t)(s & 1) * 65536;
      }

      floatx4 acc[4][2];
#pragma unroll
      for (int mt = 0; mt < 4; ++mt)
#pragma unroll
        for (int nt = 0; nt < 2; ++nt)
          acc[mt][nt] = (floatx4){0.f, 0.f, 0.f, 0.f};

      if (layer) gemm_step<8, KP1>(kb, 1024, keo, lm, xb, hb, wlds, acc);
      else       gemm_step<6, KP0>(kb,  512, keo, lm, xb, hb, wlds, acc);

      // two-half reduction (8 partials -> 4 slots -> sum) + fused cell update
#pragma unroll
      for (int h = 0; h < 2; ++h) {
        if (wave < 4) {
#pragma unroll
          for (int mi = 0; mi < 2; ++mi)
#pragma unroll
            for (int nt = 0; nt < 2; ++nt)
#pragma unroll
              for (int r = 0; r < 4; ++r)
                red[wave][mi * 16 + quad * 4 + r][nt * 16 + lm] = acc[2 * h + mi][nt][r];
        }
        __syncthreads();
        if (wave >= 4) {
#pragma unroll
          for (int mi = 0; mi < 2; ++mi)
#pragma unroll
            for (int nt = 0; nt < 2; ++nt)
#pragma unroll
              for (int r = 0; r < 4; ++r)
                red[wave - 4][mi * 16 + quad * 4 + r][nt * 16 + lm] += acc[2 * h + mi][nt][r];
        }
        __syncthreads();
        if (tid < 256) {
          const int b = h * 32 + bl_c;
          float g0 = bsum[0], g1 = bsum[1], g2 = bsum[2], g3 = bsum[3];
#pragma unroll
          for (int v = 0; v < 4; ++v) {
            g0 += red[v][bl_c][jl_c];
            g1 += red[v][bl_c][8 + jl_c];
            g2 += red[v][bl_c][16 + jl_c];
            g3 += red[v][bl_c][24 + jl_c];
          }
          const float ig = sigmoidf_(g0);
          const float fg = sigmoidf_(g1);
          const float gg = tanhf_(g2);
          const float og = sigmoidf_(g3);
          const float cn = fg * cv[h] + ig * gg;
          cv[h] = cn;
          const float hn = og * tanhf_(cn);
          const unsigned short hb16 = f2bf(hn);
          hw[b * HID + jb + jl_c] = hb16;
          if (layer && t == slv[h]) lh[b * HID + jb + jl_c] = hb16;
        }
        if (h == 0) __syncthreads();
      }
    }

    grid_barrier();
  }

  // ===== FC: pred[64, 32000] = last_h @ fc_w^T + fc_b  (fcw f32 -> bf16 on the fly)
  const int colbase = wg * 125;                 // 256 * 125 = 32000
  const int col  = colbase + wave * 16 + lm;    // 8 waves x 16 = 128 cols
  const int colc = (col < NCLS) ? col : (NCLS - 1);
  floatx4 facc[4];
  {
    const unsigned short* ab[4];
#pragma unroll
    for (int mt = 0; mt < 4; ++mt) ab[mt] = lh + (mt * 16 + lm) * HID;
    const float* bb = fcw + (size_t)colc * HID;

#pragma unroll
    for (int mt = 0; mt < 4; ++mt) facc[mt] = (floatx4){0.f, 0.f, 0.f, 0.f};

    short8 a0[4], a1[4], b0, b1;
    auto ld = [&](short8 (&A)[4], short8& B, int kbase) {
      const int off = kbase + keo;
      float4 v0 = *(const float4*)(bb + off);
      float4 v1 = *(const float4*)(bb + off + 4);
      short8 bv;
      bv[0] = (short)f2bf(v0.x); bv[1] = (short)f2bf(v0.y);
      bv[2] = (short)f2bf(v0.z); bv[3] = (short)f2bf(v0.w);
      bv[4] = (short)f2bf(v1.x); bv[5] = (short)f2bf(v1.y);
      bv[6] = (short)f2bf(v1.z); bv[7] = (short)f2bf(v1.w);
      B = bv;
#pragma unroll
      for (int mt = 0; mt < 4; ++mt)
        A[mt] = *reinterpret_cast<const short8*>(ab[mt] + off);
    };
    ld(a0, b0, 0);
#pragma unroll
    for (int kt = 0; kt < 30; kt += 2) {
      ld(a1, b1, (kt + 1) * 32);
#pragma unroll
      for (int mt = 0; mt < 4; ++mt)
        facc[mt] = __builtin_amdgcn_mfma_f32_16x16x32_bf16(a0[mt], b0, facc[mt], 0, 0, 0);
      ld(a0, b0, (kt + 2) * 32);
#pragma unroll
      for (int mt = 0; mt < 4; ++mt)
        facc[mt] = __builtin_amdgcn_mfma_f32_16x16x32_bf16(a1[mt], b1, facc[mt], 0, 0, 0);
    }
    ld(a1, b1, 31 * 32);
#pragma unroll
    for (int mt = 0; mt < 4; ++mt)
      facc[mt] = __builtin_amdgcn_mfma_f32_16x16x32_bf16(a0[mt], b0, facc[mt], 0, 0, 0);
#pragma unroll
    for (int mt = 0; mt < 4; ++mt)
      facc[mt] = __builtin_amdgcn_mfma_f32_16x16x32_bf16(a1[mt], b1, facc[mt], 0, 0, 0);
  }

  grid_barrier();   // everyone done reading lh before stores clobber scratch

  if (col < colbase + 125) {
    const float bias = fcb[col];
#pragma unroll
    for (int mt = 0; mt < 4; ++mt)
#pragma unroll
      for (int r = 0; r < 4; ++r) {
        const int row = mt * 16 + quad * 4 + r;
        out[(size_t)row * NCLS + col] = facc[mt][r] + bias;
      }
  }
}

extern "C" void kernel_launch(void* const* d_in, const int* in_sizes, int n_in,
                              void* d_out, int out_size, void* d_ws, size_t ws_size,
                              hipStream_t stream) {
  (void)in_sizes; (void)n_in; (void)out_size; (void)ws_size;
  const int*   feat = (const int*)d_in[0];
  const float* emb  = (const float*)d_in[1];
  const float* wih0 = (const float*)d_in[2];
  const float* whh0 = (const float*)d_in[3];
  const float* bih0 = (const float*)d_in[4];
  const float* bhh0 = (const float*)d_in[5];
  const float* wih1 = (const float*)d_in[6];
  const float* whh1 = (const float*)d_in[7];
  const float* bih1 = (const float*)d_in[8];
  const float* bhh1 = (const float*)d_in[9];
  const float* fcw  = (const float*)d_in[10];
  const float* fcb  = (const float*)d_in[11];
  float*       out  = (float*)d_out;
  unsigned*    bar  = (unsigned*)d_ws;

  // zero bf16 scratch inside d_out (h0 x2, h1 x2, lh, xbuf x2) + barrier counters
  hipMemsetAsync(d_out, 0, 786432, stream);
  hipMemsetAsync(d_ws, 0, 64, stream);

  void* args[] = { &feat, &emb, &wih0, &whh0, &bih0, &bhh0, &wih1, &whh1,
                   &bih1, &bhh1, &fcw, &fcb, &out, &bar };
  hipLaunchCooperativeKernel((const void*)lstm_kernel, dim3(NWG), dim3(NTHR),
                             args, 0, stream);
}

// Round 4
// 7209.406 us; speedup vs baseline: 2.2672x; 2.2672x over previous
//
#include <hip/hip_runtime.h>

#define NWG   256
#define NTHR  512
#define TSEQ  512
#define HID   1024
#define NCLS  32000
#define KP1   2056   // padded LDS row stride (elements), layer 1 (K=2048); stride words ≡4 mod 8 -> 2-way (free)
#define KP0   1544   // padded LDS row stride (elements), layer 0 (K=1536)

typedef __attribute__((ext_vector_type(8))) short short8;
typedef __attribute__((ext_vector_type(4))) float floatx4;

struct AB { short8 a[4]; short8 b[2]; };

__device__ __forceinline__ unsigned short f2bf(float f) {
  union { float f; unsigned u; } c; c.f = f;
  unsigned r = c.u + 0x7fffu + ((c.u >> 16) & 1u);
  return (unsigned short)(r >> 16);
}
__device__ __forceinline__ float sigmoidf_(float x) {
  x = fminf(30.f, fmaxf(-30.f, x));
  return 1.f / (1.f + __expf(-x));
}
__device__ __forceinline__ float tanhf_(float x) {
  x = fminf(15.f, fmaxf(-15.f, x));
  float e = __expf(2.f * x);
  return (e - 1.f) / (e + 1.f);
}
// relaxed agent-scope u32 store: write-through (sc1), no fence needed at release
__device__ __forceinline__ void st_u32_agent(unsigned* p, unsigned v) {
  __hip_atomic_store(p, v, __ATOMIC_RELAXED, __HIP_MEMORY_SCOPE_AGENT);
}

__device__ __forceinline__ void mfma8(const AB& f, floatx4 (&acc)[4][2]) {
#pragma unroll
  for (int mt = 0; mt < 4; ++mt)
#pragma unroll
    for (int nt = 0; nt < 2; ++nt)
      acc[mt][nt] = __builtin_amdgcn_mfma_f32_16x16x32_bf16(f.a[mt], f.b[nt], acc[mt][nt], 0, 0, 0);
}

// One wave's K-slice of C[64,32] += A[64,Kslice] * W^T.  A from global (bf16),
// W from LDS (bf16, row-major [32][KPAD]).  hb pre-shifted so addr = hb + k for k>=kx.
template <int NKT, int KPAD>
__device__ __forceinline__ void gemm_step(
    int kb, int kx, int keo, int lm,
    const unsigned short* const (&xb)[4], const unsigned short* const (&hb)[4],
    const unsigned short* wl, floatx4 (&acc)[4][2])
{
  AB f0, f1;
  auto ld = [&](AB& f, int kt) {
    const int k = kb + kt * 32;
    const int off = k + keo;
#pragma unroll
    for (int nt = 0; nt < 2; ++nt)
      f.b[nt] = *reinterpret_cast<const short8*>(wl + (nt * 16 + lm) * KPAD + off);
    const bool inx = k < kx;   // wave-uniform; 32-tiles never straddle kx
#pragma unroll
    for (int mt = 0; mt < 4; ++mt)
      f.a[mt] = *reinterpret_cast<const short8*>((inx ? xb[mt] : hb[mt]) + off);
  };
  ld(f0, 0);
#pragma unroll
  for (int kt = 0; kt + 2 < NKT; kt += 2) {
    ld(f1, kt + 1);
    mfma8(f0, acc);
    ld(f0, kt + 2);
    mfma8(f1, acc);
  }
  ld(f1, NKT - 1);
  mfma8(f0, acc);
  mfma8(f1, acc);
}

__global__ void __launch_bounds__(NTHR, 1)
lstm_kernel(const int* __restrict__ feat,
            const float* __restrict__ emb,
            const float* __restrict__ wih0, const float* __restrict__ whh0,
            const float* __restrict__ bih0, const float* __restrict__ bhh0,
            const float* __restrict__ wih1, const float* __restrict__ whh1,
            const float* __restrict__ bih1, const float* __restrict__ bhh1,
            const float* __restrict__ fcw, const float* __restrict__ fcb,
            float* __restrict__ out,
            unsigned* __restrict__ bar)
{
  const int tid  = threadIdx.x;
  const int wg   = blockIdx.x;
  const int wave = tid >> 6;
  const int lane = tid & 63;
  const int quad = lane >> 4;
  const int lm   = lane & 15;
  const int keo  = quad * 8;

  // bf16 scratch inside d_out (f32 [64,32000] = 8.19 MB); FC overwrites at end.
  unsigned short* sc   = (unsigned short*)out;
  unsigned short* h0   = sc;              // 2 x [64][1024]
  unsigned short* h1   = sc + 131072;     // 2 x [64][1024]
  unsigned short* lh   = sc + 262144;     // [64][1024]
  unsigned short* xbuf = sc + 327680;     // 2 x [64][512]

  const int layer = (wg >= 128) ? 1 : 0;
  const int wl_id = wg & 127;
  const int jb = wl_id * 8;               // this WG owns H-columns [jb, jb+8)

  __shared__ unsigned short wlds[32 * KP1];  // 131,584 B: this WG's weights, bf16
  __shared__ float red[4][32][40];           // 20,480 B: K-split partials
  __shared__ int   sl[64];

  // ---- one-time: weights f32 -> bf16 -> LDS  (rows r: gate=r>>3, col=jb+(r&7)) ----
  {
    const float* wih = layer ? wih1 : wih0;
    const float* whh = layer ? whh1 : whh0;
    const int KX   = layer ? 1024 : 512;
    const int KTOT = layer ? 2048 : 1536;
    const int KPAD = layer ? KP1 : KP0;
    for (int r = 0; r < 32; ++r) {
      const int gr = (r >> 3) * HID + jb + (r & 7);
      for (int e4 = tid; e4 < (KTOT >> 2); e4 += NTHR) {
        const int k = e4 * 4;
        float4 v = (k < KX) ? *(const float4*)(wih + (size_t)gr * KX + k)
                            : *(const float4*)(whh + (size_t)gr * 1024 + (k - KX));
        ushort4 u; u.x = f2bf(v.x); u.y = f2bf(v.y); u.z = f2bf(v.z); u.w = f2bf(v.w);
        *(ushort4*)(wlds + r * KPAD + k) = u;
      }
    }
    if (layer && tid < 64) {   // seq_lens
      int cnt = 0;
      const int* fr = feat + tid * TSEQ;
      for (int k = 0; k < TSEQ; k += 4)
        cnt += (fr[k] != 31999) + (fr[k + 1] != 31999) +
               (fr[k + 2] != 31999) + (fr[k + 3] != 31999);
      int v = cnt - 1; if (v < 0) v = 0;
      sl[tid] = v;
    }
  }
  __syncthreads();

  // ---- per-cell-thread persistent state (tid<256: b = half*32 + (tid>>3), jl = tid&7)
  float bsum[4];
  float cv[2] = {0.f, 0.f};
  int   slv[2] = {0, 0};
  const int jl_c = tid & 7;
  const int bl_c = tid >> 3;     // 0..31 for tid<256
  if (tid < 256) {
    const float* bih = layer ? bih1 : bih0;
    const float* bhh = layer ? bhh1 : bhh0;
    const int gj = jb + jl_c;
#pragma unroll
    for (int g = 0; g < 4; ++g) bsum[g] = bih[g * HID + gj] + bhh[g * HID + gj];
    if (layer) { slv[0] = sl[bl_c]; slv[1] = sl[32 + bl_c]; }
  }

  // ---- pre-fill xbuf slot 0 with t=0 (layer-0 WG wl_id -> batch wl_id>>1, half wl_id&1)
  if (!layer && tid < 256) {
    const int b = wl_id >> 1;
    const int off = (wl_id & 1) * 256 + tid;
    unsigned xv = f2bf(emb[(size_t)feat[b * TSEQ + 0] * 512 + off]);
    unsigned ov = (unsigned)__shfl_xor((int)xv, 1, 64);
    if ((tid & 1) == 0)
      st_u32_agent((unsigned*)(xbuf + b * 512 + off), xv | (ov << 16));
  }

  // ---- two-level grid barrier: relaxed atomics only; ONE acquire fence per wake
  unsigned target = 0;
  auto grid_barrier = [&]() {
    ++target;
    __builtin_amdgcn_s_waitcnt(0);   // each wave drains its agent-scope stores (at LIC)
    __syncthreads();
    if (tid == 0) {
      const unsigned grp = (unsigned)wg & 7u;
      unsigned old = __hip_atomic_fetch_add(&bar[grp * 32], 1u, __ATOMIC_RELAXED, __HIP_MEMORY_SCOPE_AGENT);
      if (old == target * 32u - 1u) {          // last of my group
        unsigned mo = __hip_atomic_fetch_add(&bar[1024], 1u, __ATOMIC_RELAXED, __HIP_MEMORY_SCOPE_AGENT);
        if (mo == target * 8u - 1u) {          // last group overall -> release
          __hip_atomic_store(&bar[1040], target, __ATOMIC_RELAXED, __HIP_MEMORY_SCOPE_AGENT);
        } else {
          while (__hip_atomic_load(&bar[1040], __ATOMIC_RELAXED, __HIP_MEMORY_SCOPE_AGENT) < target)
            __builtin_amdgcn_s_sleep(1);
        }
      } else {
        while (__hip_atomic_load(&bar[1040], __ATOMIC_RELAXED, __HIP_MEMORY_SCOPE_AGENT) < target)
          __builtin_amdgcn_s_sleep(1);
      }
      __builtin_amdgcn_fence(__ATOMIC_ACQUIRE, "agent");  // single waitcnt+buffer_inv
    }
    __syncthreads();
  };

  grid_barrier();   // xbuf[0] visible to all layer-0 WGs

  const int KW = layer ? 256 : 192;    // K per wave (8-way K-split)
  const int kb = wave * KW;

  for (int s = 0; s <= TSEQ; ++s) {
    const bool active = layer ? (s >= 1) : (s < TSEQ);
    const int t = layer ? (s - 1) : s;

    if (active) {
      // stage next x_t (layer-0 only): packed u32 agent stores
      if (!layer && (s + 1 < TSEQ) && tid < 256) {
        const int b = wl_id >> 1;
        const int off = (wl_id & 1) * 256 + tid;
        unsigned xv = f2bf(emb[(size_t)feat[b * TSEQ + (s + 1)] * 512 + off]);
        unsigned ov = (unsigned)__shfl_xor((int)xv, 1, 64);
        if ((tid & 1) == 0)
          st_u32_agent((unsigned*)(xbuf + ((s + 1) & 1) * 32768 + b * 512 + off), xv | (ov << 16));
      }

      // A-source pointers for this step
      const unsigned short* xb[4];
      const unsigned short* hb[4];
      unsigned short* hw;
      if (layer) {
        const unsigned short* h0r = h0 + (size_t)((s - 1) & 1) * 65536;  // layer-0 out @ t
        const unsigned short* h1r = h1 + (size_t)(s & 1) * 65536;        // own prev h (t-1)
#pragma unroll
        for (int mt = 0; mt < 4; ++mt) {
          const int row = mt * 16 + lm;
          xb[mt] = h0r + row * HID;
          hb[mt] = h1r + row * HID - 1024;
        }
        hw = h1 + (size_t)(t & 1) * 65536;
      } else {
        const unsigned short* xq  = xbuf + (size_t)(s & 1) * 32768;
        const unsigned short* h0r = h0 + (size_t)((s + 1) & 1) * 65536;
#pragma unroll
        for (int mt = 0; mt < 4; ++mt) {
          const int row = mt * 16 + lm;
          xb[mt] = xq + row * 512;
          hb[mt] = h0r + row * HID - 512;
        }
        hw = h0 + (size_t)(s & 1) * 65536;
      }

      floatx4 acc[4][2];
#pragma unroll
      for (int mt = 0; mt < 4; ++mt)
#pragma unroll
        for (int nt = 0; nt < 2; ++nt)
          acc[mt][nt] = (floatx4){0.f, 0.f, 0.f, 0.f};

      if (layer) gemm_step<8, KP1>(kb, 1024, keo, lm, xb, hb, wlds, acc);
      else       gemm_step<6, KP0>(kb,  512, keo, lm, xb, hb, wlds, acc);

      // two-half reduction (8 partials -> 4 slots -> sum) + fused cell update
#pragma unroll
      for (int h = 0; h < 2; ++h) {
        if (wave < 4) {
#pragma unroll
          for (int mi = 0; mi < 2; ++mi)
#pragma unroll
            for (int nt = 0; nt < 2; ++nt)
#pragma unroll
              for (int r = 0; r < 4; ++r)
                red[wave][mi * 16 + quad * 4 + r][nt * 16 + lm] = acc[2 * h + mi][nt][r];
        }
        __syncthreads();
        if (wave >= 4) {
#pragma unroll
          for (int mi = 0; mi < 2; ++mi)
#pragma unroll
            for (int nt = 0; nt < 2; ++nt)
#pragma unroll
              for (int r = 0; r < 4; ++r)
                red[wave - 4][mi * 16 + quad * 4 + r][nt * 16 + lm] += acc[2 * h + mi][nt][r];
        }
        __syncthreads();
        if (tid < 256) {
          const int b = h * 32 + bl_c;
          float g0 = bsum[0], g1 = bsum[1], g2 = bsum[2], g3 = bsum[3];
#pragma unroll
          for (int v = 0; v < 4; ++v) {
            g0 += red[v][bl_c][jl_c];
            g1 += red[v][bl_c][8 + jl_c];
            g2 += red[v][bl_c][16 + jl_c];
            g3 += red[v][bl_c][24 + jl_c];
          }
          const float ig = sigmoidf_(g0);
          const float fg = sigmoidf_(g1);
          const float gg = tanhf_(g2);
          const float og = sigmoidf_(g3);
          const float cn = fg * cv[h] + ig * gg;
          cv[h] = cn;
          const float hn = og * tanhf_(cn);
          // pack pair (jl even|odd) -> u32 agent store (write-through)
          unsigned my = f2bf(hn);
          unsigned ov = (unsigned)__shfl_xor((int)my, 1, 64);
          if ((tid & 1) == 0) {
            const unsigned packed = my | (ov << 16);
            st_u32_agent((unsigned*)(hw + b * HID + jb + jl_c), packed);
            if (layer && t == slv[h])
              st_u32_agent((unsigned*)(lh + b * HID + jb + jl_c), packed);
          }
        }
        if (h == 0) __syncthreads();
      }
    }

    grid_barrier();
  }

  // ===== FC: pred[64, 32000] = last_h @ fc_w^T + fc_b  (fcw f32 -> bf16 on the fly)
  const int colbase = wg * 125;                 // 256 * 125 = 32000
  const int col  = colbase + wave * 16 + lm;    // 8 waves x 16 = 128 cols
  const int colc = (col < NCLS) ? col : (NCLS - 1);
  floatx4 facc[4];
  {
    const unsigned short* ab[4];
#pragma unroll
    for (int mt = 0; mt < 4; ++mt) ab[mt] = lh + (mt * 16 + lm) * HID;
    const float* bb = fcw + (size_t)colc * HID;

#pragma unroll
    for (int mt = 0; mt < 4; ++mt) facc[mt] = (floatx4){0.f, 0.f, 0.f, 0.f};

    short8 a0[4], a1[4], b0, b1;
    auto ld = [&](short8 (&A)[4], short8& B, int kbase) {
      const int off = kbase + keo;
      float4 v0 = *(const float4*)(bb + off);
      float4 v1 = *(const float4*)(bb + off + 4);
      short8 bv;
      bv[0] = (short)f2bf(v0.x); bv[1] = (short)f2bf(v0.y);
      bv[2] = (short)f2bf(v0.z); bv[3] = (short)f2bf(v0.w);
      bv[4] = (short)f2bf(v1.x); bv[5] = (short)f2bf(v1.y);
      bv[6] = (short)f2bf(v1.z); bv[7] = (short)f2bf(v1.w);
      B = bv;
#pragma unroll
      for (int mt = 0; mt < 4; ++mt)
        A[mt] = *reinterpret_cast<const short8*>(ab[mt] + off);
    };
    ld(a0, b0, 0);
#pragma unroll
    for (int kt = 0; kt < 30; kt += 2) {
      ld(a1, b1, (kt + 1) * 32);
#pragma unroll
      for (int mt = 0; mt < 4; ++mt)
        facc[mt] = __builtin_amdgcn_mfma_f32_16x16x32_bf16(a0[mt], b0, facc[mt], 0, 0, 0);
      ld(a0, b0, (kt + 2) * 32);
#pragma unroll
      for (int mt = 0; mt < 4; ++mt)
        facc[mt] = __builtin_amdgcn_mfma_f32_16x16x32_bf16(a1[mt], b1, facc[mt], 0, 0, 0);
    }
    ld(a1, b1, 31 * 32);
#pragma unroll
    for (int mt = 0; mt < 4; ++mt)
      facc[mt] = __builtin_amdgcn_mfma_f32_16x16x32_bf16(a0[mt], b0, facc[mt], 0, 0, 0);
#pragma unroll
    for (int mt = 0; mt < 4; ++mt)
      facc[mt] = __builtin_amdgcn_mfma_f32_16x16x32_bf16(a1[mt], b1, facc[mt], 0, 0, 0);
  }

  grid_barrier();   // everyone done reading lh before stores clobber scratch

  if (col < colbase + 125) {
    const float bias = fcb[col];
#pragma unroll
    for (int mt = 0; mt < 4; ++mt)
#pragma unroll
      for (int r = 0; r < 4; ++r) {
        const int row = mt * 16 + quad * 4 + r;
        out[(size_t)row * NCLS + col] = facc[mt][r] + bias;
      }
  }
}

extern "C" void kernel_launch(void* const* d_in, const int* in_sizes, int n_in,
                              void* d_out, int out_size, void* d_ws, size_t ws_size,
                              hipStream_t stream) {
  (void)in_sizes; (void)n_in; (void)out_size; (void)ws_size;
  const int*   feat = (const int*)d_in[0];
  const float* emb  = (const float*)d_in[1];
  const float* wih0 = (const float*)d_in[2];
  const float* whh0 = (const float*)d_in[3];
  const float* bih0 = (const float*)d_in[4];
  const float* bhh0 = (const float*)d_in[5];
  const float* wih1 = (const float*)d_in[6];
  const float* whh1 = (const float*)d_in[7];
  const float* bih1 = (const float*)d_in[8];
  const float* bhh1 = (const float*)d_in[9];
  const float* fcw  = (const float*)d_in[10];
  const float* fcb  = (const float*)d_in[11];
  float*       out  = (float*)d_out;
  unsigned*    bar  = (unsigned*)d_ws;

  // zero bf16 scratch inside d_out (h0 x2, h1 x2, lh, xbuf x2) + barrier counters/flag
  hipMemsetAsync(d_out, 0, 786432, stream);
  hipMemsetAsync(d_ws, 0, 8192, stream);

  void* args[] = { &feat, &emb, &wih0, &whh0, &bih0, &bhh0, &wih1, &whh1,
                   &bih1, &bhh1, &fcw, &fcb, &out, &bar };
  hipLaunchCooperativeKernel((const void*)lstm_kernel, dim3(NWG), dim3(NTHR),
                             args, 0, stream);
}